// Round 2
// baseline (27.425 us; speedup 1.0000x reference)
//
#include <hip/hip_runtime.h>

// Problem constants: x [B=8, C=8, H=256, W=256] f32, theta [O=8, 2, 3] f32
// out [B=8, O=8, H=256, W=256] f32.
#define BDIM 8
#define CDIM 8
#define ODIM 8
#define HDIM 256
#define WDIM 256
#define HW   (HDIM * WDIM)      // 65536
#define HW4  (HW / 4)           // 16384 float4s per [H,W] plane

// Kernel 1: xbar[b,h,w] = mean_c x[b,c,h,w]. Linear-op hoist: bilinear
// sampling is linear in x and the grid is c-independent, so mean-over-c
// commutes with the sampler. 8x fewer gathers downstream.
__global__ __launch_bounds__(256) void mean_c_kernel(const float4* __restrict__ x,
                                                     float4* __restrict__ xbar) {
    int t = blockIdx.x * blockDim.x + threadIdx.x;   // 0 .. B*HW4-1
    int b = t >> 14;                                  // / HW4
    int r = t & (HW4 - 1);
    const float4* p = x + (size_t)b * CDIM * HW4 + r;
    float sx = 0.f, sy = 0.f, sz = 0.f, sw = 0.f;
#pragma unroll
    for (int c = 0; c < CDIM; ++c) {
        float4 v = p[(size_t)c * HW4];
        sx += v.x; sy += v.y; sz += v.z; sw += v.w;
    }
    const float inv = 1.0f / CDIM;
    float4 s;
    s.x = sx * inv; s.y = sy * inv; s.z = sz * inv; s.w = sw * inv;
    xbar[t] = s;
}

// Kernel 2: each thread computes 4 consecutive output pixels (float4 store).
// Affine grid + bilinear sample of L2-resident xbar[b] (2 MiB total).
__global__ __launch_bounds__(256) void sample_kernel(const float* __restrict__ xbar,
                                                     const float* __restrict__ theta,
                                                     float* __restrict__ out) {
    int t = blockIdx.x * blockDim.x + threadIdx.x;   // 0 .. HW/4-1 per plane
    int o = blockIdx.y;
    int b = blockIdx.z;
    int h  = t >> 6;          // 64 threads per row, 4 px each
    int w0 = (t & 63) << 2;   // starting w of this thread's 4 pixels

    float t00 = theta[o * 6 + 0], t01 = theta[o * 6 + 1], t02 = theta[o * 6 + 2];
    float t10 = theta[o * 6 + 3], t11 = theta[o * 6 + 4], t12 = theta[o * 6 + 5];

    // linspace(-1, 1, 256): step 2/255
    float ys = -1.0f + (float)h * (2.0f / 255.0f);
    // row-constant parts
    float gx_row = t01 * ys + t02;
    float gy_row = t11 * ys + t12;

    const float* xb = xbar + (size_t)b * HW;

    float4 r;
    float* rp = &r.x;
#pragma unroll
    for (int k = 0; k < 4; ++k) {
        int w = w0 + k;
        float xs = -1.0f + (float)w * (2.0f / 255.0f);
        float gx = t00 * xs + gx_row;
        float gy = t10 * xs + gy_row;

        // to pixel coords (align_corners=True)
        float ix = (gx + 1.0f) * 0.5f * (WDIM - 1);
        float iy = (gy + 1.0f) * 0.5f * (HDIM - 1);

        float ix0 = floorf(ix), iy0 = floorf(iy);
        float ix1 = ix0 + 1.0f, iy1 = iy0 + 1.0f;
        float wx1 = ix - ix0, wx0 = 1.0f - wx1;
        float wy1 = iy - iy0, wy0 = 1.0f - wy1;

        bool vx0 = (ix0 >= 0.0f) && (ix0 <= (float)(WDIM - 1));
        bool vx1 = (ix1 >= 0.0f) && (ix1 <= (float)(WDIM - 1));
        bool vy0 = (iy0 >= 0.0f) && (iy0 <= (float)(HDIM - 1));
        bool vy1 = (iy1 >= 0.0f) && (iy1 <= (float)(HDIM - 1));

        int jx0 = (int)fminf(fmaxf(ix0, 0.0f), (float)(WDIM - 1));
        int jx1 = (int)fminf(fmaxf(ix1, 0.0f), (float)(WDIM - 1));
        int jy0 = (int)fminf(fmaxf(iy0, 0.0f), (float)(HDIM - 1));
        int jy1 = (int)fminf(fmaxf(iy1, 0.0f), (float)(HDIM - 1));

        float v00 = (vy0 && vx0) ? xb[jy0 * WDIM + jx0] : 0.0f;
        float v01 = (vy0 && vx1) ? xb[jy0 * WDIM + jx1] : 0.0f;
        float v10 = (vy1 && vx0) ? xb[jy1 * WDIM + jx0] : 0.0f;
        float v11 = (vy1 && vx1) ? xb[jy1 * WDIM + jx1] : 0.0f;

        rp[k] = v00 * (wy0 * wx0) + v01 * (wy0 * wx1)
              + v10 * (wy1 * wx0) + v11 * (wy1 * wx1);
    }

    float4* op = (float4*)(out + ((((size_t)b * ODIM + o) * HDIM + h) << 8) + w0);
    *op = r;
}

extern "C" void kernel_launch(void* const* d_in, const int* in_sizes, int n_in,
                              void* d_out, int out_size, void* d_ws, size_t ws_size,
                              hipStream_t stream) {
    const float* x     = (const float*)d_in[0];
    const float* theta = (const float*)d_in[1];
    float* out  = (float*)d_out;
    float* xbar = (float*)d_ws;   // needs B*HW*4 = 2 MiB of workspace

    // Kernel 1: B*HW4 = 131072 float4 threads
    mean_c_kernel<<<dim3((BDIM * HW4) / 256), dim3(256), 0, stream>>>(
        (const float4*)x, (float4*)xbar);

    // Kernel 2: one thread per 4 output pixels
    dim3 grid(HW4 / 256, ODIM, BDIM);   // 64 x 8 x 8 blocks
    sample_kernel<<<grid, dim3(256), 0, stream>>>(xbar, theta, out);
}

// Round 4
// 23.048 us; speedup vs baseline: 1.1899x; 1.1899x over previous
//
#include <hip/hip_runtime.h>

// Problem constants: x [B=8, C=8, H=256, W=256] f32, theta [O=8, 2, 3] f32
// out [B=8, O=8, H=256, W=256] f32.
#define BDIM 8
#define CDIM 8
#define ODIM 8
#define HDIM 256
#define WDIM 256
#define HW   (HDIM * WDIM)      // 65536
#define HW4  (HW / 4)           // 16384 float4s per [H,W] plane

typedef float f32x4 __attribute__((ext_vector_type(4)));

// Kernel 1: xbar[b,h,w] = mean_c x[b,c,h,w]. Linear-op hoist: bilinear
// sampling is linear in x and the grid is c-independent, so mean-over-c
// commutes with the sampler. 8x fewer gathers downstream.
__global__ __launch_bounds__(256) void mean_c_kernel(const f32x4* __restrict__ x,
                                                     f32x4* __restrict__ xbar) {
    int t = blockIdx.x * blockDim.x + threadIdx.x;   // 0 .. B*HW4-1
    int b = t >> 14;                                  // / HW4
    int r = t & (HW4 - 1);
    const f32x4* p = x + (size_t)b * CDIM * HW4 + r;
    f32x4 s = {0.f, 0.f, 0.f, 0.f};
#pragma unroll
    for (int c = 0; c < CDIM; ++c) {
        // nontemporal: x is read-once; don't evict xbar from L2
        f32x4 v = __builtin_nontemporal_load(&p[(size_t)c * HW4]);
        s += v;
    }
    s *= (1.0f / CDIM);
    xbar[t] = s;
}

// Kernel 2: 2D wave tiling. Each wave owns an 8x8 output tile; block of
// 256 threads = 2x2 waves = 16x16 px tile. Gather footprint per wave is the
// affine image of an 8x8 square (~15-30 cache lines) instead of a 1x64 row
// segment (~64 lines) -> gather line-throughput bound relieved ~2.5-4x.
// Per output row a block covers 16 px = exactly one 64B line, merged in the
// block's own L2 -> no partial-line write amplification.
__global__ __launch_bounds__(256) void sample_kernel(const float* __restrict__ xbar,
                                                     const float* __restrict__ theta,
                                                     float* __restrict__ out) {
    int o = blockIdx.y;
    int b = blockIdx.z;
    int tx = blockIdx.x & 15;        // 16 tiles of 16 px across W
    int ty = blockIdx.x >> 4;        // 16 tiles of 16 px across H
    int wave = threadIdx.x >> 6;     // 0..3 -> 2x2 wave grid
    int lane = threadIdx.x & 63;
    int h = (ty << 4) + ((wave >> 1) << 3) + (lane >> 3);
    int w = (tx << 4) + ((wave & 1) << 3) + (lane & 7);

    float t00 = theta[o * 6 + 0], t01 = theta[o * 6 + 1], t02 = theta[o * 6 + 2];
    float t10 = theta[o * 6 + 3], t11 = theta[o * 6 + 4], t12 = theta[o * 6 + 5];

    // linspace(-1, 1, 256): step 2/255
    float xs = -1.0f + (float)w * (2.0f / 255.0f);
    float ys = -1.0f + (float)h * (2.0f / 255.0f);

    float gx = t00 * xs + t01 * ys + t02;
    float gy = t10 * xs + t11 * ys + t12;

    // to pixel coords (align_corners=True)
    float ix = (gx + 1.0f) * 0.5f * (WDIM - 1);
    float iy = (gy + 1.0f) * 0.5f * (HDIM - 1);

    float ix0 = floorf(ix), iy0 = floorf(iy);
    float ix1 = ix0 + 1.0f, iy1 = iy0 + 1.0f;
    float wx1 = ix - ix0, wx0 = 1.0f - wx1;
    float wy1 = iy - iy0, wy0 = 1.0f - wy1;

    bool vx0 = (ix0 >= 0.0f) && (ix0 <= (float)(WDIM - 1));
    bool vx1 = (ix1 >= 0.0f) && (ix1 <= (float)(WDIM - 1));
    bool vy0 = (iy0 >= 0.0f) && (iy0 <= (float)(HDIM - 1));
    bool vy1 = (iy1 >= 0.0f) && (iy1 <= (float)(HDIM - 1));

    int jx0 = (int)fminf(fmaxf(ix0, 0.0f), (float)(WDIM - 1));
    int jx1 = (int)fminf(fmaxf(ix1, 0.0f), (float)(WDIM - 1));
    int jy0 = (int)fminf(fmaxf(iy0, 0.0f), (float)(HDIM - 1));
    int jy1 = (int)fminf(fmaxf(iy1, 0.0f), (float)(HDIM - 1));

    const float* xb = xbar + (size_t)b * HW;
    float v00 = (vy0 && vx0) ? xb[jy0 * WDIM + jx0] : 0.0f;
    float v01 = (vy0 && vx1) ? xb[jy0 * WDIM + jx1] : 0.0f;
    float v10 = (vy1 && vx0) ? xb[jy1 * WDIM + jx0] : 0.0f;
    float v11 = (vy1 && vx1) ? xb[jy1 * WDIM + jx1] : 0.0f;

    float r = v00 * (wy0 * wx0) + v01 * (wy0 * wx1)
            + v10 * (wy1 * wx0) + v11 * (wy1 * wx1);

    out[((((size_t)b * ODIM + o) * HDIM + h) << 8) + w] = r;
}

extern "C" void kernel_launch(void* const* d_in, const int* in_sizes, int n_in,
                              void* d_out, int out_size, void* d_ws, size_t ws_size,
                              hipStream_t stream) {
    const float* x     = (const float*)d_in[0];
    const float* theta = (const float*)d_in[1];
    float* out  = (float*)d_out;
    float* xbar = (float*)d_ws;   // needs B*HW*4 = 2 MiB of workspace

    // Kernel 1: B*HW4 = 131072 float4 threads
    mean_c_kernel<<<dim3((BDIM * HW4) / 256), dim3(256), 0, stream>>>(
        (const f32x4*)x, (f32x4*)xbar);

    // Kernel 2: 16x16 px tile per block, 256 tiles per plane
    dim3 grid(256, ODIM, BDIM);
    sample_kernel<<<grid, dim3(256), 0, stream>>>(xbar, theta, out);
}